// Round 3
// baseline (739.451 us; speedup 1.0000x reference)
//
#include <hip/hip_runtime.h>
#include <math.h>

// Problem constants
#define H 128
#define Wd 128
#define SW 113          // Wd-16+1 (== SH)

// LDS swizzle: row r, float4-chunk c (0..31) stored at
//   phys = (c & 24) | ((c ^ ((r>>1)&7)) & 7)
// Compute lanes (p consecutive, r=2p+ro) get all 8 bank-groups per 8-lane
// b128 phase -> conflict-free.
__device__ __forceinline__ int swz32(int c, int r) {
    return (c & 24) | ((c ^ (r >> 1)) & 7);
}

// ---------------- prep: wn = w / sqrt(sum(w^2)/n), n = 16384 ----------------
__global__ __launch_bounds__(256) void prep_wn(const float* __restrict__ w,
                                               float* __restrict__ wn) {
    __shared__ float red[256];
    int t = threadIdx.x;
    float wv = w[t];
    red[t] = wv * wv;
    __syncthreads();
    for (int off = 128; off > 0; off >>= 1) {
        if (t < off) red[t] += red[t + off];
        __syncthreads();
    }
    float denom = sqrtf(red[0] / 16384.0f);
    wn[t] = wv / denom;
}

// Load one swizzled input row segment (48 floats = 12 b128) into regs.
__device__ __forceinline__ void load_row(const float4* __restrict__ t4, int r,
                                         int xt, float* s) {
    int k = (r >> 1) & 7;
    int rb = r << 5;
#pragma unroll
    for (int q = 0; q < 12; ++q) {
        int cq = 8 * xt + q;
        int phys = (cq & 24) | ((cq ^ k) & 7);
        float4 v = t4[rb | phys];
        s[4 * q + 0] = v.x;
        s[4 * q + 1] = v.y;
        s[4 * q + 2] = v.z;
        s[4 * q + 3] = v.w;
    }
}

// acc[x] += corr(s, wr)[x] for x = 0..31  (512 FMAs)
__device__ __forceinline__ void fma_row(float* acc, const float* s,
                                        const float* __restrict__ wr) {
#pragma unroll
    for (int kj = 0; kj < 16; ++kj) {
        float wv = wr[kj];
#pragma unroll
        for (int x = 0; x < 32; ++x)
            acc[x] = __builtin_fmaf(s[x + kj], wv, acc[x]);
    }
}

// ---------------- main: scores -> argmax|.| -> scatter smax*wn ----------------
// One block (256 thr) per sample. Thread (p = tid&63, xt = tid>>6) computes
// score rows y0=2p, y0+1 at x = 32*xt .. 32*xt+31. The 17 input rows are each
// read ONCE (12 ds_read_b128) and feed both score rows (2048 FMA per 24 reads
// in the steady-state loop body). A/B register double-buffer hides ds latency.
__global__ __launch_bounds__(256, 2) void gtpca_main(
    const float* __restrict__ in, const float* __restrict__ wn,
    float* __restrict__ out) {
    __shared__ float4 tile4[4096];           // exactly 64 KB
    float* tile = (float*)tile4;

    const int tid = threadIdx.x;
    const int b = blockIdx.x;
    const float4* in4 = (const float4*)(in + (size_t)b * (H * Wd));

    // ---- load sample into LDS (swizzled) ----
#pragma unroll
    for (int i = 0; i < 16; ++i) {
        int g = tid + i * 256;               // float4 index 0..4095
        int y = g >> 5;                      // row
        int c = g & 31;                      // chunk in row
        tile4[(y << 5) | swz32(c, y)] = in4[g];
    }
    __syncthreads();

    const int p = tid & 63;                  // row-pair index
    const int xt = tid >> 6;                 // x-tile 0..3 (wave-uniform)
    float best_a = -1.0f;
    int best_i = 0x7FFFFFFF;
    float best_v = 0.0f;

    if (p < 57) {
        const int y0 = 2 * p;                // score rows y0, y0+1
        float acc0[32], acc1[32];
#pragma unroll
        for (int i = 0; i < 32; ++i) { acc0[i] = 0.0f; acc1[i] = 0.0f; }
        float A[48], B[48];

        load_row(tile4, y0, xt, A);          // row y0
        load_row(tile4, y0 + 1, xt, B);      // row y0+1
        fma_row(acc0, A, wn);                // ki=0 -> y0

        // steady state: consume rows y0+ro-1 (B) and y0+ro (A), prefetch next
#pragma unroll 1
        for (int ro = 2; ro < 16; ro += 2) { // ro = 2,4,...,14
            load_row(tile4, y0 + ro, xt, A);
            fma_row(acc0, B, wn + 16 * (ro - 1));   // ki=ro-1 -> y0
            fma_row(acc1, B, wn + 16 * (ro - 2));   // ki=ro-2 -> y0+1
            load_row(tile4, y0 + ro + 1, xt, B);
            fma_row(acc0, A, wn + 16 * ro);         // ki=ro   -> y0
            fma_row(acc1, A, wn + 16 * (ro - 1));   // ki=ro-1 -> y0+1
        }
        // pending: B = row y0+15; last row y0+16 (clamp p=56; acc1 discarded)
        int rlast = y0 + 16; if (rlast > 127) rlast = 127;
        load_row(tile4, rlast, xt, A);
        fma_row(acc0, B, wn + 240);          // ki=15, row y0+15 -> y0 done
        fma_row(acc1, B, wn + 224);          // ki=14           -> y0+1
        fma_row(acc1, A, wn + 240);          // ki=15, row y0+16 -> y0+1 done

        // ---- per-thread argmax candidates ----
        const int xb = 32 * xt;
        const int bidx = y0 * SW + xb;
#pragma unroll
        for (int x = 0; x < 32; ++x) {
            if (xb + x < SW) {
                float a = fabsf(acc0[x]);
                int idx = bidx + x;
                if (a > best_a || (a == best_a && idx < best_i)) {
                    best_a = a; best_i = idx; best_v = acc0[x];
                }
            }
        }
        if (y0 + 1 < SW) {
#pragma unroll
            for (int x = 0; x < 32; ++x) {
                if (xb + x < SW) {
                    float a = fabsf(acc1[x]);
                    int idx = bidx + SW + x;
                    if (a > best_a || (a == best_a && idx < best_i)) {
                        best_a = a; best_i = idx; best_v = acc1[x];
                    }
                }
            }
        }
    }

    // ---- block reduction (alias tile; everyone is done reading it) ----
    __syncthreads();
    float* red_a = tile;                      // [256]
    int* red_i = (int*)(tile + 256);          // [256]
    float* red_v = tile + 512;                // [256]
    red_a[tid] = best_a;
    red_i[tid] = best_i;
    red_v[tid] = best_v;
    __syncthreads();
    for (int off = 128; off > 0; off >>= 1) {
        if (tid < off) {
            float a2 = red_a[tid + off];
            int i2 = red_i[tid + off];
            float v2 = red_v[tid + off];
            if (a2 > red_a[tid] || (a2 == red_a[tid] && i2 < red_i[tid])) {
                red_a[tid] = a2;
                red_i[tid] = i2;
                red_v[tid] = v2;
            }
        }
        __syncthreads();
    }
    int bi = red_i[0];
    float sv = red_v[0] * (1.0f / 16384.0f);  // exact: /2^14
    int rr = bi / SW;
    int cc = bi % SW;

    // ---- output: zeros + smax*wn block at (rr,cc) ----
    float4* out4 = (float4*)(out + (size_t)b * (H * Wd));
#pragma unroll
    for (int i = 0; i < 16; ++i) {
        int g = tid + i * 256;
        int orow = g >> 5;
        int ocol = (g & 31) << 2;
        float4 v = {0.0f, 0.0f, 0.0f, 0.0f};
        int dr = orow - rr;
        if ((unsigned)dr < 16u) {
            float* vp = (float*)&v;
#pragma unroll
            for (int k = 0; k < 4; ++k) {
                int dc = ocol + k - cc;
                if ((unsigned)dc < 16u) vp[k] = sv * wn[dr * 16 + dc];
            }
        }
        out4[g] = v;
    }
}

extern "C" void kernel_launch(void* const* d_in, const int* in_sizes, int n_in,
                              void* d_out, int out_size, void* d_ws, size_t ws_size,
                              hipStream_t stream) {
    const float* in = (const float*)d_in[0];   // (4096,128,128) fp32
    const float* w = (const float*)d_in[1];    // (16,16) fp32
    float* out = (float*)d_out;                // (4096,128,128) fp32
    float* wn = (float*)d_ws;                  // 256 floats scratch

    prep_wn<<<1, 256, 0, stream>>>(w, wn);
    gtpca_main<<<4096, 256, 0, stream>>>(in, wn, out);
}

// Round 4
// 659.980 us; speedup vs baseline: 1.1204x; 1.1204x over previous
//
#include <hip/hip_runtime.h>
#include <math.h>

// Problem constants
#define H 128
#define Wd 128
#define SW 113          // Wd-16+1 (== SH)
#define NROW1 80        // rows staged in phase 1 (LDS = 80*512B = 40 KB)

// LDS swizzle keyed by SLOT: slot s, float4-chunk c stored at
//   phys = (c & 24) | ((c ^ ((s>>1)&7)) & 7)
// Compute lanes have consecutive slot>>1 across each 8-lane b128 phase ->
// all 8 bank-groups distinct -> conflict-free. Row r -> slot (r<80 ? r : r-80).
__device__ __forceinline__ int swz(int c, int slot) {
    return (c & 24) | ((c ^ (slot >> 1)) & 7);
}

// ---------------- prep: wn = w / sqrt(sum(w^2)/n), n = 16384 ----------------
__global__ __launch_bounds__(256) void prep_wn(const float* __restrict__ w,
                                               float* __restrict__ wn) {
    __shared__ float red[256];
    int t = threadIdx.x;
    float wv = w[t];
    red[t] = wv * wv;
    __syncthreads();
    for (int off = 128; off > 0; off >>= 1) {
        if (t < off) red[t] += red[t + off];
        __syncthreads();
    }
    float denom = sqrtf(red[0] / 16384.0f);
    wn[t] = wv / denom;
}

// Load one swizzled input row segment (32 floats = 8 b128) into regs.
// xt=7 reads wrap harmlessly (feeds only x>=113, discarded by guard).
__device__ __forceinline__ void load_seg(const float4* __restrict__ t4, int r,
                                         int xt, float* s) {
    int slot = (r < NROW1) ? r : r - NROW1;
    int k = (slot >> 1) & 7;
    int base = slot << 5;
#pragma unroll
    for (int q = 0; q < 8; ++q) {
        int cq = 4 * xt + q;
        int phys = (cq & 24) | ((cq ^ k) & 7);
        float4 v = t4[base | phys];
        s[4 * q + 0] = v.x;
        s[4 * q + 1] = v.y;
        s[4 * q + 2] = v.z;
        s[4 * q + 3] = v.w;
    }
}

// acc[x] += corr(s, wr)[x], x = 0..15  (256 FMAs)
__device__ __forceinline__ void fma_row16(float* acc, const float* s,
                                          const float* __restrict__ wr) {
#pragma unroll
    for (int kj = 0; kj < 16; ++kj) {
        float wv = wr[kj];
#pragma unroll
        for (int x = 0; x < 16; ++x)
            acc[x] = __builtin_fmaf(s[x + kj], wv, acc[x]);
    }
}

// Compute score rows y0, y0+1 at x = 16*xt .. 16*xt+15; update running argmax.
__device__ __forceinline__ void task(const float4* __restrict__ t4,
                                     const float* __restrict__ wn,
                                     int y0, int xt, bool row1_valid,
                                     float& best_a, int& best_i, float& best_v) {
    float acc0[16], acc1[16];
#pragma unroll
    for (int i = 0; i < 16; ++i) { acc0[i] = 0.0f; acc1[i] = 0.0f; }
    float seg[32];

    load_seg(t4, y0, xt, seg);
    fma_row16(acc0, seg, wn);                    // ki=0 -> y0
#pragma unroll 1
    for (int ro = 1; ro < 16; ++ro) {
        load_seg(t4, y0 + ro, xt, seg);
        fma_row16(acc0, seg, wn + 16 * ro);      // ki=ro   -> y0
        fma_row16(acc1, seg, wn + 16 * (ro - 1)); // ki=ro-1 -> y0+1
    }
    int rlast = y0 + 16; if (rlast > 127) rlast = 127;  // clamp (acc1 discarded)
    load_seg(t4, rlast, xt, seg);
    fma_row16(acc1, seg, wn + 240);              // ki=15 -> y0+1

    const int xb = 16 * xt;
    const int bidx = y0 * SW + xb;
#pragma unroll
    for (int x = 0; x < 16; ++x) {
        if (xb + x < SW) {
            float a = fabsf(acc0[x]);
            int idx = bidx + x;
            if (a > best_a || (a == best_a && idx < best_i)) {
                best_a = a; best_i = idx; best_v = acc0[x];
            }
        }
    }
    if (row1_valid) {
#pragma unroll
        for (int x = 0; x < 16; ++x) {
            if (xb + x < SW) {
                float a = fabsf(acc1[x]);
                int idx = bidx + SW + x;
                if (a > best_a || (a == best_a && idx < best_i)) {
                    best_a = a; best_i = idx; best_v = acc1[x];
                }
            }
        }
    }
}

// ---------------- main: scores -> argmax|.| -> scatter smax*wn ----------------
// One block (256 thr) per sample, 40 KB LDS -> 4 blocks/CU (vs 2 at 64 KB).
// Phase 1: stage rows 0..79, compute score rows 0..63 (pairs p=0..31).
// Phase 2: restage rows 80..127 into slots 0..47, compute rows 64..112.
__global__ __launch_bounds__(256, 4) void gtpca_main(
    const float* __restrict__ in, const float* __restrict__ wn,
    float* __restrict__ out) {
    __shared__ float4 tile4[2560];               // 40 KB
    float* tile = (float*)tile4;

    const int tid = threadIdx.x;
    const int b = blockIdx.x;
    const float4* in4 = (const float4*)(in + (size_t)b * (H * Wd));

    // ---- phase-1 staging: rows 0..79 (slots 0..79) ----
#pragma unroll
    for (int i = 0; i < 10; ++i) {
        int g = tid + i * 256;                   // float4 index 0..2559
        int slot = g >> 5;
        int c = g & 31;
        tile4[(slot << 5) | swz(c, slot)] = in4[g];
    }
    __syncthreads();

    const int p = tid & 31;
    const int xt = tid >> 5;                     // 0..7, 16 x each
    float best_a = -1.0f;
    int best_i = 0x7FFFFFFF;
    float best_v = 0.0f;

    // ---- phase-1 compute: score rows 0..63 ----
    task(tile4, wn, 2 * p, xt, true, best_a, best_i, best_v);
    __syncthreads();

    // ---- phase-2 staging: rows 80..127 -> slots 0..47 ----
#pragma unroll
    for (int i = 0; i < 6; ++i) {
        int g = tid + i * 256;                   // 0..1535
        int slot = g >> 5;                       // 0..47
        int c = g & 31;
        tile4[(slot << 5) | swz(c, slot)] = in4[2560 + g];
    }
    __syncthreads();

    // ---- phase-2 compute: score rows 64..112 (pairs p=0..24) ----
    if (p < 25) {
        int y0 = 64 + 2 * p;                     // 64..112
        task(tile4, wn, y0, xt, (y0 + 1) < SW, best_a, best_i, best_v);
    }

    // ---- block reduction (alias tile; everyone is done reading it) ----
    __syncthreads();
    float* red_a = tile;                         // [256]
    int* red_i = (int*)(tile + 256);             // [256]
    float* red_v = tile + 512;                   // [256]
    red_a[tid] = best_a;
    red_i[tid] = best_i;
    red_v[tid] = best_v;
    __syncthreads();
    for (int off = 128; off > 0; off >>= 1) {
        if (tid < off) {
            float a2 = red_a[tid + off];
            int i2 = red_i[tid + off];
            float v2 = red_v[tid + off];
            if (a2 > red_a[tid] || (a2 == red_a[tid] && i2 < red_i[tid])) {
                red_a[tid] = a2;
                red_i[tid] = i2;
                red_v[tid] = v2;
            }
        }
        __syncthreads();
    }
    int bi = red_i[0];
    float sv = red_v[0] * (1.0f / 16384.0f);     // exact: /2^14
    int rr = bi / SW;
    int cc = bi % SW;

    // ---- output: zeros + smax*wn block at (rr,cc) ----
    float4* out4 = (float4*)(out + (size_t)b * (H * Wd));
#pragma unroll
    for (int i = 0; i < 16; ++i) {
        int g = tid + i * 256;
        int orow = g >> 5;
        int ocol = (g & 31) << 2;
        float4 v = {0.0f, 0.0f, 0.0f, 0.0f};
        int dr = orow - rr;
        if ((unsigned)dr < 16u) {
            float* vp = (float*)&v;
#pragma unroll
            for (int k = 0; k < 4; ++k) {
                int dc = ocol + k - cc;
                if ((unsigned)dc < 16u) vp[k] = sv * wn[dr * 16 + dc];
            }
        }
        out4[g] = v;
    }
}

extern "C" void kernel_launch(void* const* d_in, const int* in_sizes, int n_in,
                              void* d_out, int out_size, void* d_ws, size_t ws_size,
                              hipStream_t stream) {
    const float* in = (const float*)d_in[0];   // (4096,128,128) fp32
    const float* w = (const float*)d_in[1];    // (16,16) fp32
    float* out = (float*)d_out;                // (4096,128,128) fp32
    float* wn = (float*)d_ws;                  // 256 floats scratch

    prep_wn<<<1, 256, 0, stream>>>(w, wn);
    gtpca_main<<<4096, 256, 0, stream>>>(in, wn, out);
}